// Round 1
// baseline (1109.933 us; speedup 1.0000x reference)
//
#include <hip/hip_runtime.h>
#include <math.h>

#define B_ 2
#define S_ 1024
#define D_ 128
#define N_ 256
#define L_ 2
#define H_ 2
#define V_ 32000

#define INV2PI 0.15915494309189535f
#define PHI_F 1.61803398874989484f

__device__ __forceinline__ float fract_(float x) { return x - floorf(x); }
// v_sin/v_cos take revolutions; reduce first.
__device__ __forceinline__ float fsin_(float th) { return __builtin_amdgcn_sinf(fract_(th * INV2PI)); }
__device__ __forceinline__ float fcos_(float th) { return __builtin_amdgcn_cosf(fract_(th * INV2PI)); }

// ---------------- gather embed rows: emb_g[b,t,c] = embed[ids[b,t]][c] ----------------
__global__ __launch_bounds__(256) void k_gather(const int* __restrict__ ids,
                                                const float* __restrict__ embed,
                                                float* __restrict__ eg) {
    int i = blockIdx.x * 256 + threadIdx.x;      // B*S*256
    int c = i & 255, t = (i >> 8) & 1023, b = i >> 18;
    int id = ids[b * S_ + t];
    eg[i] = embed[(size_t)id * 256 + c];
}

// ---------------- euler scan (sequential over t, contracting) ----------------
__global__ __launch_bounds__(128) void k_euler(const float* __restrict__ eg,
                                               float* __restrict__ sr, float* __restrict__ si,
                                               float* __restrict__ x, float* __restrict__ Kb) {
    int b = blockIdx.x;          // 2 blocks
    int d = threadIdx.x;         // 128
    const float* p0 = eg + (size_t)b * S_ * 256 + d;
    float h = 0.f;               // h_real + h_imag carry
    double tp = 0.0;             // 2*t*PHI mod 2pi
    const double DTP = 2.0 * 1.6180339887498949;
    const double TWO_PI = 6.283185307179586476925286766559;
    float wA[8], bA[8], wB[8], bB[8];
#pragma unroll
    for (int k = 0; k < 8; ++k) { wA[k] = p0[k * 256]; bA[k] = p0[k * 256 + 128]; }
    for (int g = 0; g < 128; ++g) {
        if (g < 127) {
            const float* p = p0 + (size_t)(g + 1) * 8 * 256;
#pragma unroll
            for (int k = 0; k < 8; ++k) { wB[k] = p[k * 256]; bB[k] = p[k * 256 + 128]; }
        }
#pragma unroll
        for (int k = 0; k < 8; ++k) {
            int t = g * 8 + k;
            float inv = 1.f / (1.f + fabsf(wA[k]));
            float th = fmaf(h, inv, 2.f * bA[k] + (float)tp);
            float u = fract_(th * INV2PI);
            float sn = __builtin_amdgcn_sinf(u);
            float cs = __builtin_amdgcn_cosf(u);
            size_t idx = ((size_t)b * S_ + t) * D_ + d;
            sr[idx] = cs; si[idx] = sn; x[idx] = cs + sn;
            size_t ki = ((size_t)b * S_ + t) * 256 + d;
            Kb[ki] = cs; Kb[ki + 128] = sn;
            h = cs + sn;
            tp += DTP; if (tp >= TWO_PI) tp -= TWO_PI;
        }
#pragma unroll
        for (int k = 0; k < 8; ++k) { wA[k] = wB[k]; bA[k] = bB[k]; }
    }
}

// ---------------- Q = cos(states/wl_q + b_q + t*phi), layout (B,H,S,2D) ----------------
__global__ __launch_bounds__(256) void k_q(const float* __restrict__ sr, const float* __restrict__ si,
                                           const float* __restrict__ wq, const float* __restrict__ bq,
                                           float* __restrict__ Q) {
    int i = blockIdx.x * 256 + threadIdx.x;      // B*H*S*256
    int c = i & 255;
    int s = (i >> 8) & 1023;
    int bh = i >> 18;           // b*H + h
    int h = bh & 1, b = bh >> 1;
    int d = c & 127;
    const float* st = (c < 128) ? sr : si;
    float v = st[((size_t)b * S_ + s) * D_ + d];
    float w = wq[h * D_ + d], bb = bq[h * D_ + d];
    float th = v / (1.f + fabsf(w)) + bb + (float)s * PHI_F;
    Q[i] = fcos_(th);
}

// ---------------- scores = Q K^T / 16, causal (skip kt>qt tiles) ----------------
__global__ __launch_bounds__(256) void k_scores(const float* __restrict__ Q,
                                                const float* __restrict__ Kb,
                                                float* __restrict__ sc) {
    int kt = blockIdx.x, qt = blockIdx.y, bh = blockIdx.z;
    if (kt > qt) return;
    const float* Qp = Q + (size_t)bh * S_ * 256;
    const float* Kp = Kb + (size_t)(bh >> 1) * S_ * 256;
    float* Cp = sc + (size_t)bh * S_ * S_;
    __shared__ float As[16][68], Bs[16][68];   // [k][m] transposed
    int tid = threadIdx.x;
    int tx = tid & 15, ty = tid >> 4;
    int lr = tid >> 2, lc = (tid & 3) * 4;
    float acc[4][4] = {};
    for (int kc = 0; kc < 256; kc += 16) {
        float4 av = *(const float4*)&Qp[(size_t)(qt * 64 + lr) * 256 + kc + lc];
        float4 bv = *(const float4*)&Kp[(size_t)(kt * 64 + lr) * 256 + kc + lc];
        __syncthreads();
        As[lc + 0][lr] = av.x; As[lc + 1][lr] = av.y; As[lc + 2][lr] = av.z; As[lc + 3][lr] = av.w;
        Bs[lc + 0][lr] = bv.x; Bs[lc + 1][lr] = bv.y; Bs[lc + 2][lr] = bv.z; Bs[lc + 3][lr] = bv.w;
        __syncthreads();
#pragma unroll
        for (int kk = 0; kk < 16; ++kk) {
            float4 a4 = *(const float4*)&As[kk][ty * 4];
            float4 b4 = *(const float4*)&Bs[kk][tx * 4];
            float a[4] = {a4.x, a4.y, a4.z, a4.w};
            float b[4] = {b4.x, b4.y, b4.z, b4.w};
#pragma unroll
            for (int i = 0; i < 4; ++i)
#pragma unroll
                for (int j = 0; j < 4; ++j) acc[i][j] = fmaf(a[i], b[j], acc[i][j]);
        }
    }
    const float s16 = 0.0625f;
    if (kt < qt) {
#pragma unroll
        for (int i = 0; i < 4; ++i) {
            int q = qt * 64 + ty * 4 + i;
            float4 v = {acc[i][0] * s16, acc[i][1] * s16, acc[i][2] * s16, acc[i][3] * s16};
            *(float4*)&Cp[(size_t)q * S_ + kt * 64 + tx * 4] = v;
        }
    } else {
#pragma unroll
        for (int i = 0; i < 4; ++i) {
            int q = qt * 64 + ty * 4 + i;
#pragma unroll
            for (int j = 0; j < 4; ++j) {
                int k = kt * 64 + tx * 4 + j;
                if (k <= q) Cp[(size_t)q * S_ + k] = acc[i][j] * s16;
            }
        }
    }
}

// ---------------- softmax in place; zero above diagonal ----------------
__global__ __launch_bounds__(256) void k_softmax(float* __restrict__ sc) {
    int row = blockIdx.x;            // (bh*S + q)
    int q = row & 1023;
    float* r = sc + (size_t)row * S_;
    int tid = threadIdx.x;
    __shared__ float red[256];
    float m = -1e30f;
    for (int k = tid; k <= q; k += 256) m = fmaxf(m, r[k]);
    red[tid] = m; __syncthreads();
    for (int s = 128; s > 0; s >>= 1) { if (tid < s) red[tid] = fmaxf(red[tid], red[tid + s]); __syncthreads(); }
    m = red[0]; __syncthreads();
    float sum = 0.f;
    for (int k = tid; k <= q; k += 256) sum += __expf(r[k] - m);
    red[tid] = sum; __syncthreads();
    for (int s = 128; s > 0; s >>= 1) { if (tid < s) red[tid] += red[tid + s]; __syncthreads(); }
    float rs = 1.f / red[0];
    for (int k = tid; k <= q; k += 256) r[k] = __expf(r[k] - m) * rs;
    for (int k = q + 1 + tid; k < S_; k += 256) r[k] = 0.f;
}

// ---------------- retrieved = attn @ K  (attn has zeros above diag) ----------------
__global__ __launch_bounds__(256) void k_pv(const float* __restrict__ A,
                                            const float* __restrict__ Kb,
                                            float* __restrict__ R) {
    int nt = blockIdx.x, qt = blockIdx.y, bh = blockIdx.z;
    const float* Ap = A + (size_t)bh * S_ * S_;
    const float* Kp = Kb + (size_t)(bh >> 1) * S_ * 256;
    float* Rp = R + (size_t)bh * S_ * 256;
    __shared__ float As[16][68];    // [k][m]
    __shared__ float Bs[16][68];    // [k][n]
    int tid = threadIdx.x;
    int tx = tid & 15, ty = tid >> 4;
    int lr = tid >> 2, lc = (tid & 3) * 4;
    int br = tid >> 4, bc = (tid & 15) * 4;
    float acc[4][4] = {};
    int kmax = qt * 64 + 64;
    for (int kc = 0; kc < kmax; kc += 16) {
        float4 av = *(const float4*)&Ap[(size_t)(qt * 64 + lr) * S_ + kc + lc];
        float4 bv = *(const float4*)&Kp[(size_t)(kc + br) * 256 + nt * 64 + bc];
        __syncthreads();
        As[lc + 0][lr] = av.x; As[lc + 1][lr] = av.y; As[lc + 2][lr] = av.z; As[lc + 3][lr] = av.w;
        *(float4*)&Bs[br][bc] = bv;
        __syncthreads();
#pragma unroll
        for (int kk = 0; kk < 16; ++kk) {
            float4 a4 = *(const float4*)&As[kk][ty * 4];
            float4 b4 = *(const float4*)&Bs[kk][tx * 4];
            float a[4] = {a4.x, a4.y, a4.z, a4.w};
            float b[4] = {b4.x, b4.y, b4.z, b4.w};
#pragma unroll
            for (int i = 0; i < 4; ++i)
#pragma unroll
                for (int j = 0; j < 4; ++j) acc[i][j] = fmaf(a[i], b[j], acc[i][j]);
        }
    }
#pragma unroll
    for (int i = 0; i < 4; ++i) {
        float4 v = {acc[i][0], acc[i][1], acc[i][2], acc[i][3]};
        *(float4*)&Rp[(size_t)(qt * 64 + ty * 4 + i) * 256 + nt * 64 + tx * 4] = v;
    }
}

// ---------------- EMA as 64-tap FIR ((1-a)^64 ~ 2e-21), heads+halves summed ----------------
__global__ __launch_bounds__(256) void k_ema(const float* __restrict__ R,
                                             const float* __restrict__ ap,
                                             float* __restrict__ comb) {
    int blk = blockIdx.x;            // b*S + t
    int b = blk >> 10, t = blk & 1023;
    int dim = threadIdx.x;           // 256
    __shared__ float wsh[2][64];
    __shared__ float sh[256];
    if (dim < 128) {
        int h = dim >> 6, j = dim & 63;
        float a = 1.f / (1.f + __expf(-ap[h]));
        float om = 1.f - a;
        wsh[h][j] = a * exp2f((float)j * log2f(om));
    }
    __syncthreads();
    int jmax = t < 63 ? t : 63;
    float acc = 0.f;
    for (int h = 0; h < 2; ++h) {
        const float* base = R + ((size_t)(b * 2 + h) * S_ + t) * 256 + dim;
        float s = 0.f;
        for (int j = 0; j <= jmax; ++j) s = fmaf(wsh[h][j], base[-j * 256], s);
        acc += s;
    }
    sh[dim] = acc;
    __syncthreads();
    if (dim < 128) comb[((size_t)b * S_ + t) * D_ + dim] = sh[dim] + sh[dim + 128];
}

// ---------------- FFN prep: transpose params to (D,N) / (N,D) ----------------
__global__ __launch_bounds__(256) void k_prep(const float* __restrict__ W, const float* __restrict__ Bp,
                                              const float* __restrict__ ac, const float* __restrict__ as2,
                                              const float* __restrict__ pc, const float* __restrict__ ps,
                                              float* __restrict__ iwT, float* __restrict__ bpT,
                                              float* __restrict__ acT, float* __restrict__ asT,
                                              float* __restrict__ pcT, float* __restrict__ psT) {
    int i = blockIdx.x * 256 + threadIdx.x;    // L*N*D, i = (l,n,d)
    int d = i & 127, n = (i >> 7) & 255, l = i >> 15;
    int ti = (l * 128 + d) * 256 + n;          // (l,d,n)
    iwT[ti] = 1.f / (1.f + fabsf(W[i]));
    bpT[ti] = Bp[i];
    acT[ti] = ac[i];
    asT[ti] = as2[i];
    // proj_cos is (L,D,N): element (l,d,n) sits at ti -> write (L,N,D)
    pcT[(l * 256 + n) * 128 + d] = pc[ti];
    psT[(l * 256 + n) * 128 + d] = ps[ti];
}

// ---------------- FFN phase 1: cos_sum/sin_sum, 8 rows per block ----------------
__global__ __launch_bounds__(256) void k_ffn1(const float* __restrict__ x,
                                              const float* __restrict__ iwT, const float* __restrict__ bpT,
                                              const float* __restrict__ acT, const float* __restrict__ asT,
                                              float* __restrict__ cs, float* __restrict__ ss) {
    int row0 = blockIdx.x * 8;
    int n = threadIdx.x;             // 256
    __shared__ float xs[8][128];
#pragma unroll
    for (int i = 0; i < 4; ++i) {
        int idx = n + i * 256;
        xs[idx >> 7][idx & 127] = x[(size_t)row0 * D_ + idx];
    }
    __syncthreads();
    float ac_[8] = {}, as_[8] = {};
    for (int d = 0; d < 128; ++d) {
        float iw = iwT[d * 256 + n];
        float bp = bpT[d * 256 + n];
        float wc = acT[d * 256 + n];
        float ws2 = asT[d * 256 + n];
#pragma unroll
        for (int r = 0; r < 8; ++r) {
            float th = fmaf(xs[r][d], iw, bp);
            float u = fract_(th * INV2PI);
            ac_[r] = fmaf(__builtin_amdgcn_cosf(u), wc, ac_[r]);
            as_[r] = fmaf(__builtin_amdgcn_sinf(u), ws2, as_[r]);
        }
    }
#pragma unroll
    for (int r = 0; r < 8; ++r) {
        cs[(size_t)(row0 + r) * 256 + n] = ac_[r];
        ss[(size_t)(row0 + r) * 256 + n] = as_[r];
    }
}

// ---------------- FFN phase 2: proj + silu, 8 rows per block ----------------
__global__ __launch_bounds__(128) void k_ffn2(const float* __restrict__ cs, const float* __restrict__ ss,
                                              const float* __restrict__ pcT, const float* __restrict__ psT,
                                              float* __restrict__ res) {
    int row0 = blockIdx.x * 8;
    int d = threadIdx.x;             // 128
    __shared__ float csh[8][256], ssh[8][256];
#pragma unroll
    for (int i = 0; i < 16; ++i) {
        int idx = d + i * 128;
        csh[idx >> 8][idx & 255] = cs[(size_t)row0 * 256 + idx];
        ssh[idx >> 8][idx & 255] = ss[(size_t)row0 * 256 + idx];
    }
    __syncthreads();
    float acc[8] = {};
    for (int nn = 0; nn < 256; ++nn) {
        float pc = pcT[nn * 128 + d], ps = psT[nn * 128 + d];
#pragma unroll
        for (int r = 0; r < 8; ++r)
            acc[r] = fmaf(csh[r][nn], pc, fmaf(ssh[r][nn], ps, acc[r]));
    }
#pragma unroll
    for (int r = 0; r < 8; ++r) {
        float v = acc[r];
        res[(size_t)(row0 + r) * D_ + d] = v / (1.f + __expf(-v));   // silu
    }
}

// ---------------- x += es*(cos+sin)((comb/wl_out)+bout) + rs*res ----------------
__global__ __launch_bounds__(256) void k_update(float* __restrict__ x, const float* __restrict__ comb,
                                                const float* __restrict__ res,
                                                const float* __restrict__ wout, const float* __restrict__ bout,
                                                const float* __restrict__ esp, const float* __restrict__ rsp) {
    int i = blockIdx.x * 256 + threadIdx.x;    // B*S*D
    int d = i & 127;
    float wl = 1.f + fabsf(wout[d]);
    float th = comb[i] / wl + bout[d];
    float u = fract_(th * INV2PI);
    float echo = __builtin_amdgcn_cosf(u) + __builtin_amdgcn_sinf(u);
    x[i] += esp[0] * echo + rsp[0] * res[i];
}

// ---------------- out = x @ out_proj^T  (M=2048,N=32000,K=128) f32 ----------------
__global__ __launch_bounds__(256) void k_out(const float* __restrict__ x, const float* __restrict__ P,
                                             float* __restrict__ out) {
    __shared__ float As[8][132];   // [k][m]
    __shared__ float Bs[8][132];   // [k][n]
    int tid = threadIdx.x;
    int nt = blockIdx.x, mt = blockIdx.y;
    int mr0 = (tid >> 4) * 8, nc0 = (tid & 15) * 8;
    int lm = tid >> 1, lk = (tid & 1) * 4;
    const float* xp = x + (size_t)(mt * 128 + lm) * 128 + lk;
    const float* pp = P + (size_t)(nt * 128 + lm) * 128 + lk;
    float acc[8][8];
#pragma unroll
    for (int i = 0; i < 8; ++i)
#pragma unroll
        for (int j = 0; j < 8; ++j) acc[i][j] = 0.f;
    for (int kc = 0; kc < 128; kc += 8) {
        float4 av = *(const float4*)(xp + kc);
        float4 bv = *(const float4*)(pp + kc);
        __syncthreads();
        As[lk + 0][lm] = av.x; As[lk + 1][lm] = av.y; As[lk + 2][lm] = av.z; As[lk + 3][lm] = av.w;
        Bs[lk + 0][lm] = bv.x; Bs[lk + 1][lm] = bv.y; Bs[lk + 2][lm] = bv.z; Bs[lk + 3][lm] = bv.w;
        __syncthreads();
#pragma unroll
        for (int kk = 0; kk < 8; ++kk) {
            float4 a0 = *(const float4*)&As[kk][mr0];
            float4 a1 = *(const float4*)&As[kk][mr0 + 4];
            float4 b0 = *(const float4*)&Bs[kk][nc0];
            float4 b1 = *(const float4*)&Bs[kk][nc0 + 4];
            float a[8] = {a0.x, a0.y, a0.z, a0.w, a1.x, a1.y, a1.z, a1.w};
            float b[8] = {b0.x, b0.y, b0.z, b0.w, b1.x, b1.y, b1.z, b1.w};
#pragma unroll
            for (int i = 0; i < 8; ++i)
#pragma unroll
                for (int j = 0; j < 8; ++j) acc[i][j] = fmaf(a[i], b[j], acc[i][j]);
        }
    }
#pragma unroll
    for (int i = 0; i < 8; ++i) {
        size_t ro = (size_t)(mt * 128 + mr0 + i) * V_ + nt * 128 + nc0;
        float4 v0 = {acc[i][0], acc[i][1], acc[i][2], acc[i][3]};
        float4 v1 = {acc[i][4], acc[i][5], acc[i][6], acc[i][7]};
        *(float4*)&out[ro] = v0;
        *(float4*)&out[ro + 4] = v1;
    }
}

extern "C" void kernel_launch(void* const* d_in, const int* in_sizes, int n_in,
                              void* d_out, int out_size, void* d_ws, size_t ws_size,
                              hipStream_t stream) {
    const int* ids = (const int*)d_in[0];
    const float* embed = (const float*)d_in[1];
    const float* wq = (const float*)d_in[2];     // (L,H,D)
    const float* bq = (const float*)d_in[3];
    const float* alpha = (const float*)d_in[4];  // (L,H)
    const float* wout = (const float*)d_in[5];   // (L,D)
    const float* bout = (const float*)d_in[6];
    const float* ffnW = (const float*)d_in[7];   // (L,N,D)
    const float* ffnB = (const float*)d_in[8];
    const float* acos_ = (const float*)d_in[9];
    const float* asin_ = (const float*)d_in[10];
    const float* pcos = (const float*)d_in[11];  // (L,D,N)
    const float* psin = (const float*)d_in[12];
    const float* escl = (const float*)d_in[13];  // (L,)
    const float* rscl = (const float*)d_in[14];
    const float* oprj = (const float*)d_in[15];  // (V,D)
    float* out = (float*)d_out;
    float* ws = (float*)d_ws;

    // workspace layout (floats)
    float* EG = ws;                       // B*S*256      = 524288
    float* SR = EG + 524288;              // B*S*D        = 262144
    float* SI = SR + 262144;
    float* X  = SI + 262144;
    float* KB = X + 262144;               // B*S*256      = 524288
    float* Q  = KB + 524288;              // B*H*S*256    = 1048576
    float* SC = Q + 1048576;              // B*H*S*S      = 4194304
    float* RT = SC + 4194304;             // B*H*S*256    = 1048576
    float* CB = RT + 1048576;             // B*S*D        = 262144
    float* CS = CB + 262144;              // B*S*N        = 524288
    float* SS = CS + 524288;
    float* RS = SS + 524288;              // B*S*D        = 262144
    float* T_IW = RS + 262144;            // 6 x L*D*N (=65536 each)
    float* T_BP = T_IW + 65536;
    float* T_AC = T_BP + 65536;
    float* T_AS = T_AC + 65536;
    float* T_PC = T_AS + 65536;
    float* T_PS = T_PC + 65536;

    k_prep<<<256, 256, 0, stream>>>(ffnW, ffnB, acos_, asin_, pcos, psin,
                                    T_IW, T_BP, T_AC, T_AS, T_PC, T_PS);
    k_gather<<<2048, 256, 0, stream>>>(ids, embed, EG);
    k_euler<<<2, 128, 0, stream>>>(EG, SR, SI, X, KB);

    for (int l = 0; l < L_; ++l) {
        k_q<<<4096, 256, 0, stream>>>(SR, SI, wq + l * H_ * D_, bq + l * H_ * D_, Q);
        k_scores<<<dim3(16, 16, 4), 256, 0, stream>>>(Q, KB, SC);
        k_softmax<<<4096, 256, 0, stream>>>(SC);
        k_pv<<<dim3(4, 16, 4), 256, 0, stream>>>(SC, KB, RT);
        k_ema<<<2048, 256, 0, stream>>>(RT, alpha + l * H_, CB);
        k_ffn1<<<256, 256, 0, stream>>>(X, T_IW + l * 32768, T_BP + l * 32768,
                                        T_AC + l * 32768, T_AS + l * 32768, CS, SS);
        k_ffn2<<<256, 128, 0, stream>>>(CS, SS, T_PC + l * 32768, T_PS + l * 32768, RS);
        k_update<<<1024, 256, 0, stream>>>(X, CB, RS, wout + l * D_, bout + l * D_,
                                           escl + l, rscl + l);
    }
    k_out<<<dim3(250, 16), 256, 0, stream>>>(X, oprj, out);
}

// Round 2
// 989.182 us; speedup vs baseline: 1.1221x; 1.1221x over previous
//
#include <hip/hip_runtime.h>
#include <math.h>

#define B_ 2
#define S_ 1024
#define D_ 128
#define N_ 256
#define L_ 2
#define H_ 2
#define V_ 32000

#define INV2PI 0.15915494309189535f
#define PHI_F 1.61803398874989484f

__device__ __forceinline__ float fract_(float x) { return x - floorf(x); }
// v_sin/v_cos take revolutions; reduce first.
__device__ __forceinline__ float fsin_(float th) { return __builtin_amdgcn_sinf(fract_(th * INV2PI)); }
__device__ __forceinline__ float fcos_(float th) { return __builtin_amdgcn_cosf(fract_(th * INV2PI)); }

typedef __bf16 bf16x8 __attribute__((ext_vector_type(8)));
typedef float f32x4 __attribute__((ext_vector_type(4)));

// ---------------- gather embed rows: emb_g[b,t,c] = embed[ids[b,t]][c] ----------------
__global__ __launch_bounds__(256) void k_gather(const int* __restrict__ ids,
                                                const float* __restrict__ embed,
                                                float* __restrict__ eg) {
    int i = blockIdx.x * 256 + threadIdx.x;      // B*S*256
    int c = i & 255, t = (i >> 8) & 1023, b = i >> 18;
    int id = ids[b * S_ + t];
    eg[i] = embed[(size_t)id * 256 + c];
}

// ---------------- euler scan (sequential over t, contracting) ----------------
__global__ __launch_bounds__(128) void k_euler(const float* __restrict__ eg,
                                               float* __restrict__ sr, float* __restrict__ si,
                                               float* __restrict__ x, float* __restrict__ Kb) {
    int b = blockIdx.x;          // 2 blocks
    int d = threadIdx.x;         // 128
    const float* p0 = eg + (size_t)b * S_ * 256 + d;
    float h = 0.f;               // h_real + h_imag carry
    double tp = 0.0;             // 2*t*PHI mod 2pi
    const double DTP = 2.0 * 1.6180339887498949;
    const double TWO_PI = 6.283185307179586476925286766559;
    float wA[8], bA[8], wB[8], bB[8];
#pragma unroll
    for (int k = 0; k < 8; ++k) { wA[k] = p0[k * 256]; bA[k] = p0[k * 256 + 128]; }
    for (int g = 0; g < 128; ++g) {
        if (g < 127) {
            const float* p = p0 + (size_t)(g + 1) * 8 * 256;
#pragma unroll
            for (int k = 0; k < 8; ++k) { wB[k] = p[k * 256]; bB[k] = p[k * 256 + 128]; }
        }
#pragma unroll
        for (int k = 0; k < 8; ++k) {
            int t = g * 8 + k;
            float inv = 1.f / (1.f + fabsf(wA[k]));
            float th = fmaf(h, inv, 2.f * bA[k] + (float)tp);
            float u = fract_(th * INV2PI);
            float sn = __builtin_amdgcn_sinf(u);
            float cs = __builtin_amdgcn_cosf(u);
            size_t idx = ((size_t)b * S_ + t) * D_ + d;
            sr[idx] = cs; si[idx] = sn; x[idx] = cs + sn;
            size_t ki = ((size_t)b * S_ + t) * 256 + d;
            Kb[ki] = cs; Kb[ki + 128] = sn;
            h = cs + sn;
            tp += DTP; if (tp >= TWO_PI) tp -= TWO_PI;
        }
#pragma unroll
        for (int k = 0; k < 8; ++k) { wA[k] = wB[k]; bA[k] = bB[k]; }
    }
}

// ---------------- Q = cos(states/wl_q + b_q + t*phi), layout (B,H,S,2D) ----------------
__global__ __launch_bounds__(256) void k_q(const float* __restrict__ sr, const float* __restrict__ si,
                                           const float* __restrict__ wq, const float* __restrict__ bq,
                                           float* __restrict__ Q) {
    int i = blockIdx.x * 256 + threadIdx.x;      // B*H*S*256
    int c = i & 255;
    int s = (i >> 8) & 1023;
    int bh = i >> 18;           // b*H + h
    int h = bh & 1, b = bh >> 1;
    int d = c & 127;
    const float* st = (c < 128) ? sr : si;
    float v = st[((size_t)b * S_ + s) * D_ + d];
    float w = wq[h * D_ + d], bb = bq[h * D_ + d];
    float th = v / (1.f + fabsf(w)) + bb + (float)s * PHI_F;
    Q[i] = fcos_(th);
}

// ---------------- scores = Q K^T / 16, causal (skip kt>qt tiles) ----------------
__global__ __launch_bounds__(256) void k_scores(const float* __restrict__ Q,
                                                const float* __restrict__ Kb,
                                                float* __restrict__ sc) {
    int kt = blockIdx.x, qt = blockIdx.y, bh = blockIdx.z;
    if (kt > qt) return;
    const float* Qp = Q + (size_t)bh * S_ * 256;
    const float* Kp = Kb + (size_t)(bh >> 1) * S_ * 256;
    float* Cp = sc + (size_t)bh * S_ * S_;
    __shared__ float As[16][68], Bs[16][68];   // [k][m] transposed
    int tid = threadIdx.x;
    int tx = tid & 15, ty = tid >> 4;
    int lr = tid >> 2, lc = (tid & 3) * 4;
    float acc[4][4] = {};
    for (int kc = 0; kc < 256; kc += 16) {
        float4 av = *(const float4*)&Qp[(size_t)(qt * 64 + lr) * 256 + kc + lc];
        float4 bv = *(const float4*)&Kp[(size_t)(kt * 64 + lr) * 256 + kc + lc];
        __syncthreads();
        As[lc + 0][lr] = av.x; As[lc + 1][lr] = av.y; As[lc + 2][lr] = av.z; As[lc + 3][lr] = av.w;
        Bs[lc + 0][lr] = bv.x; Bs[lc + 1][lr] = bv.y; Bs[lc + 2][lr] = bv.z; Bs[lc + 3][lr] = bv.w;
        __syncthreads();
#pragma unroll
        for (int kk = 0; kk < 16; ++kk) {
            float4 a4 = *(const float4*)&As[kk][ty * 4];
            float4 b4 = *(const float4*)&Bs[kk][tx * 4];
            float a[4] = {a4.x, a4.y, a4.z, a4.w};
            float b[4] = {b4.x, b4.y, b4.z, b4.w};
#pragma unroll
            for (int i = 0; i < 4; ++i)
#pragma unroll
                for (int j = 0; j < 4; ++j) acc[i][j] = fmaf(a[i], b[j], acc[i][j]);
        }
    }
    const float s16 = 0.0625f;
    if (kt < qt) {
#pragma unroll
        for (int i = 0; i < 4; ++i) {
            int q = qt * 64 + ty * 4 + i;
            float4 v = {acc[i][0] * s16, acc[i][1] * s16, acc[i][2] * s16, acc[i][3] * s16};
            *(float4*)&Cp[(size_t)q * S_ + kt * 64 + tx * 4] = v;
        }
    } else {
#pragma unroll
        for (int i = 0; i < 4; ++i) {
            int q = qt * 64 + ty * 4 + i;
#pragma unroll
            for (int j = 0; j < 4; ++j) {
                int k = kt * 64 + tx * 4 + j;
                if (k <= q) Cp[(size_t)q * S_ + k] = acc[i][j] * s16;
            }
        }
    }
}

// ---------------- softmax in place; zero above diagonal ----------------
__global__ __launch_bounds__(256) void k_softmax(float* __restrict__ sc) {
    int row = blockIdx.x;            // (bh*S + q)
    int q = row & 1023;
    float* r = sc + (size_t)row * S_;
    int tid = threadIdx.x;
    __shared__ float red[256];
    float m = -1e30f;
    for (int k = tid; k <= q; k += 256) m = fmaxf(m, r[k]);
    red[tid] = m; __syncthreads();
    for (int s = 128; s > 0; s >>= 1) { if (tid < s) red[tid] = fmaxf(red[tid], red[tid + s]); __syncthreads(); }
    m = red[0]; __syncthreads();
    float sum = 0.f;
    for (int k = tid; k <= q; k += 256) sum += __expf(r[k] - m);
    red[tid] = sum; __syncthreads();
    for (int s = 128; s > 0; s >>= 1) { if (tid < s) red[tid] += red[tid + s]; __syncthreads(); }
    float rs = 1.f / red[0];
    for (int k = tid; k <= q; k += 256) r[k] = __expf(r[k] - m) * rs;
    for (int k = q + 1 + tid; k < S_; k += 256) r[k] = 0.f;
}

// ---------------- retrieved = attn @ K  (attn has zeros above diag) ----------------
__global__ __launch_bounds__(256) void k_pv(const float* __restrict__ A,
                                            const float* __restrict__ Kb,
                                            float* __restrict__ R) {
    int nt = blockIdx.x, qt = blockIdx.y, bh = blockIdx.z;
    const float* Ap = A + (size_t)bh * S_ * S_;
    const float* Kp = Kb + (size_t)(bh >> 1) * S_ * 256;
    float* Rp = R + (size_t)bh * S_ * 256;
    __shared__ float As[16][68];    // [k][m]
    __shared__ float Bs[16][68];    // [k][n]
    int tid = threadIdx.x;
    int tx = tid & 15, ty = tid >> 4;
    int lr = tid >> 2, lc = (tid & 3) * 4;
    int br = tid >> 4, bc = (tid & 15) * 4;
    float acc[4][4] = {};
    int kmax = qt * 64 + 64;
    for (int kc = 0; kc < kmax; kc += 16) {
        float4 av = *(const float4*)&Ap[(size_t)(qt * 64 + lr) * S_ + kc + lc];
        float4 bv = *(const float4*)&Kp[(size_t)(kc + br) * 256 + nt * 64 + bc];
        __syncthreads();
        As[lc + 0][lr] = av.x; As[lc + 1][lr] = av.y; As[lc + 2][lr] = av.z; As[lc + 3][lr] = av.w;
        *(float4*)&Bs[br][bc] = bv;
        __syncthreads();
#pragma unroll
        for (int kk = 0; kk < 16; ++kk) {
            float4 a4 = *(const float4*)&As[kk][ty * 4];
            float4 b4 = *(const float4*)&Bs[kk][tx * 4];
            float a[4] = {a4.x, a4.y, a4.z, a4.w};
            float b[4] = {b4.x, b4.y, b4.z, b4.w};
#pragma unroll
            for (int i = 0; i < 4; ++i)
#pragma unroll
                for (int j = 0; j < 4; ++j) acc[i][j] = fmaf(a[i], b[j], acc[i][j]);
        }
    }
#pragma unroll
    for (int i = 0; i < 4; ++i) {
        float4 v = {acc[i][0], acc[i][1], acc[i][2], acc[i][3]};
        *(float4*)&Rp[(size_t)(qt * 64 + ty * 4 + i) * 256 + nt * 64 + tx * 4] = v;
    }
}

// ---------------- EMA as 64-tap FIR ((1-a)^64 ~ 2e-21), heads+halves summed ----------------
__global__ __launch_bounds__(256) void k_ema(const float* __restrict__ R,
                                             const float* __restrict__ ap,
                                             float* __restrict__ comb) {
    int blk = blockIdx.x;            // b*S + t
    int b = blk >> 10, t = blk & 1023;
    int dim = threadIdx.x;           // 256
    __shared__ float wsh[2][64];
    __shared__ float sh[256];
    if (dim < 128) {
        int h = dim >> 6, j = dim & 63;
        float a = 1.f / (1.f + __expf(-ap[h]));
        float om = 1.f - a;
        wsh[h][j] = a * exp2f((float)j * log2f(om));
    }
    __syncthreads();
    int jmax = t < 63 ? t : 63;
    float acc = 0.f;
    for (int h = 0; h < 2; ++h) {
        const float* base = R + ((size_t)(b * 2 + h) * S_ + t) * 256 + dim;
        float s = 0.f;
        for (int j = 0; j <= jmax; ++j) s = fmaf(wsh[h][j], base[-j * 256], s);
        acc += s;
    }
    sh[dim] = acc;
    __syncthreads();
    if (dim < 128) comb[((size_t)b * S_ + t) * D_ + dim] = sh[dim] + sh[dim + 128];
}

// ---------------- FFN prep: transpose params to (D,N) / (N,D) ----------------
__global__ __launch_bounds__(256) void k_prep(const float* __restrict__ W, const float* __restrict__ Bp,
                                              const float* __restrict__ ac, const float* __restrict__ as2,
                                              const float* __restrict__ pc, const float* __restrict__ ps,
                                              float* __restrict__ iwT, float* __restrict__ bpT,
                                              float* __restrict__ acT, float* __restrict__ asT,
                                              float* __restrict__ pcT, float* __restrict__ psT) {
    int i = blockIdx.x * 256 + threadIdx.x;    // L*N*D, i = (l,n,d)
    int d = i & 127, n = (i >> 7) & 255, l = i >> 15;
    int ti = (l * 128 + d) * 256 + n;          // (l,d,n)
    iwT[ti] = 1.f / (1.f + fabsf(W[i]));
    bpT[ti] = Bp[i];
    acT[ti] = ac[i];
    asT[ti] = as2[i];
    // proj_cos is (L,D,N): element (l,d,n) sits at ti -> write (L,N,D)
    pcT[(l * 256 + n) * 128 + d] = pc[ti];
    psT[(l * 256 + n) * 128 + d] = ps[ti];
}

// ---------------- FFN phase 1: cos_sum/sin_sum, 8 rows per block ----------------
__global__ __launch_bounds__(256) void k_ffn1(const float* __restrict__ x,
                                              const float* __restrict__ iwT, const float* __restrict__ bpT,
                                              const float* __restrict__ acT, const float* __restrict__ asT,
                                              float* __restrict__ cs, float* __restrict__ ss) {
    int row0 = blockIdx.x * 8;
    int n = threadIdx.x;             // 256
    __shared__ float xs[8][128];
#pragma unroll
    for (int i = 0; i < 4; ++i) {
        int idx = n + i * 256;
        xs[idx >> 7][idx & 127] = x[(size_t)row0 * D_ + idx];
    }
    __syncthreads();
    float ac_[8] = {}, as_[8] = {};
    for (int d = 0; d < 128; ++d) {
        float iw = iwT[d * 256 + n];
        float bp = bpT[d * 256 + n];
        float wc = acT[d * 256 + n];
        float ws2 = asT[d * 256 + n];
#pragma unroll
        for (int r = 0; r < 8; ++r) {
            float th = fmaf(xs[r][d], iw, bp);
            float u = fract_(th * INV2PI);
            ac_[r] = fmaf(__builtin_amdgcn_cosf(u), wc, ac_[r]);
            as_[r] = fmaf(__builtin_amdgcn_sinf(u), ws2, as_[r]);
        }
    }
#pragma unroll
    for (int r = 0; r < 8; ++r) {
        cs[(size_t)(row0 + r) * 256 + n] = ac_[r];
        ss[(size_t)(row0 + r) * 256 + n] = as_[r];
    }
}

// ---------------- FFN phase 2: proj + silu, 8 rows per block ----------------
__global__ __launch_bounds__(128) void k_ffn2(const float* __restrict__ cs, const float* __restrict__ ss,
                                              const float* __restrict__ pcT, const float* __restrict__ psT,
                                              float* __restrict__ res) {
    int row0 = blockIdx.x * 8;
    int d = threadIdx.x;             // 128
    __shared__ float csh[8][256], ssh[8][256];
#pragma unroll
    for (int i = 0; i < 16; ++i) {
        int idx = d + i * 128;
        csh[idx >> 8][idx & 255] = cs[(size_t)row0 * 256 + idx];
        ssh[idx >> 8][idx & 255] = ss[(size_t)row0 * 256 + idx];
    }
    __syncthreads();
    float acc[8] = {};
    for (int nn = 0; nn < 256; ++nn) {
        float pc = pcT[nn * 128 + d], ps = psT[nn * 128 + d];
#pragma unroll
        for (int r = 0; r < 8; ++r)
            acc[r] = fmaf(csh[r][nn], pc, fmaf(ssh[r][nn], ps, acc[r]));
    }
#pragma unroll
    for (int r = 0; r < 8; ++r) {
        float v = acc[r];
        res[(size_t)(row0 + r) * D_ + d] = v / (1.f + __expf(-v));   // silu
    }
}

// ---------------- x += es*(cos+sin)((comb/wl_out)+bout) + rs*res ----------------
__global__ __launch_bounds__(256) void k_update(float* __restrict__ x, const float* __restrict__ comb,
                                                const float* __restrict__ res,
                                                const float* __restrict__ wout, const float* __restrict__ bout,
                                                const float* __restrict__ esp, const float* __restrict__ rsp) {
    int i = blockIdx.x * 256 + threadIdx.x;    // B*S*D
    int d = i & 127;
    float wl = 1.f + fabsf(wout[d]);
    float th = comb[i] / wl + bout[d];
    float u = fract_(th * INV2PI);
    float echo = __builtin_amdgcn_cosf(u) + __builtin_amdgcn_sinf(u);
    x[i] += esp[0] * echo + rsp[0] * res[i];
}

// ---------------- split f32 -> bf16 hi + bf16 lo for X (2048x128) and P (32000x128) ----------------
__global__ __launch_bounds__(256) void k_cvt(const float* __restrict__ X, const float* __restrict__ P,
                                             __bf16* __restrict__ Xh, __bf16* __restrict__ Xl,
                                             __bf16* __restrict__ Ph, __bf16* __restrict__ Pl) {
    int i = blockIdx.x * 256 + threadIdx.x;    // 0 .. (2048+32000)*128-1
    const int NX = 2048 * 128;
    float v; __bf16 *h, *l; int j;
    if (i < NX) { v = X[i]; h = Xh; l = Xl; j = i; }
    else { v = P[i - NX]; h = Ph; l = Pl; j = i - NX; }
    __bf16 hi = (__bf16)v;
    float lo = v - (float)hi;
    h[j] = hi;
    l[j] = (__bf16)lo;
}

// ---------------- out = X @ P^T via bf16-split MFMA (hh + hl + lh) ----------------
// block tile 128(M) x 128(N), 4 waves each 64x64 (4x4 of 16x16x32 mfma), K chunked by 32.
#define LSTR 40   // 32 k + 8 pad (bf16 elems): row stride 80 B, 16B-aligned, ~2-way banks
__global__ __launch_bounds__(256) void k_out_mfma(const __bf16* __restrict__ Xh, const __bf16* __restrict__ Xl,
                                                  const __bf16* __restrict__ Ph, const __bf16* __restrict__ Pl,
                                                  float* __restrict__ out) {
    __shared__ __bf16 Ah[128 * LSTR], Al[128 * LSTR], Bh[128 * LSTR], Bl[128 * LSTR];
    int mt = blockIdx.x, nt = blockIdx.y;
    int tid = threadIdx.x;
    int wid = tid >> 6, lane = tid & 63;
    int wy = wid >> 1, wx = wid & 1;
    int fl = lane & 15, q = lane >> 4;
    // staging map: 2 threads per row, 16 bf16 each
    int srow = tid >> 1, sseg = (tid & 1) * 16;
    const __bf16* xh = Xh + (size_t)(mt * 128 + srow) * 128 + sseg;
    const __bf16* xl = Xl + (size_t)(mt * 128 + srow) * 128 + sseg;
    const __bf16* ph = Ph + (size_t)(nt * 128 + srow) * 128 + sseg;
    const __bf16* pl = Pl + (size_t)(nt * 128 + srow) * 128 + sseg;
    int lbase = srow * LSTR + sseg;

    f32x4 acc[4][4];
#pragma unroll
    for (int i = 0; i < 4; ++i)
#pragma unroll
        for (int j = 0; j < 4; ++j) { acc[i][j][0] = 0.f; acc[i][j][1] = 0.f; acc[i][j][2] = 0.f; acc[i][j][3] = 0.f; }

    for (int kc = 0; kc < 128; kc += 32) {
        uint4 vxh0 = *(const uint4*)(xh + kc); uint4 vxh1 = *(const uint4*)(xh + kc + 8);
        uint4 vxl0 = *(const uint4*)(xl + kc); uint4 vxl1 = *(const uint4*)(xl + kc + 8);
        uint4 vph0 = *(const uint4*)(ph + kc); uint4 vph1 = *(const uint4*)(ph + kc + 8);
        uint4 vpl0 = *(const uint4*)(pl + kc); uint4 vpl1 = *(const uint4*)(pl + kc + 8);
        __syncthreads();
        *(uint4*)&Ah[lbase] = vxh0; *(uint4*)&Ah[lbase + 8] = vxh1;
        *(uint4*)&Al[lbase] = vxl0; *(uint4*)&Al[lbase + 8] = vxl1;
        *(uint4*)&Bh[lbase] = vph0; *(uint4*)&Bh[lbase + 8] = vph1;
        *(uint4*)&Bl[lbase] = vpl0; *(uint4*)&Bl[lbase + 8] = vpl1;
        __syncthreads();
        bf16x8 ah[4], al[4], bh[4], bl[4];
#pragma unroll
        for (int tm = 0; tm < 4; ++tm) {
            int r = (wy * 64 + tm * 16 + fl) * LSTR + q * 8;
            ah[tm] = *(const bf16x8*)&Ah[r];
            al[tm] = *(const bf16x8*)&Al[r];
        }
#pragma unroll
        for (int tn = 0; tn < 4; ++tn) {
            int r = (wx * 64 + tn * 16 + fl) * LSTR + q * 8;
            bh[tn] = *(const bf16x8*)&Bh[r];
            bl[tn] = *(const bf16x8*)&Bl[r];
        }
#pragma unroll
        for (int tm = 0; tm < 4; ++tm)
#pragma unroll
            for (int tn = 0; tn < 4; ++tn) {
                acc[tm][tn] = __builtin_amdgcn_mfma_f32_16x16x32_bf16(ah[tm], bh[tn], acc[tm][tn], 0, 0, 0);
                acc[tm][tn] = __builtin_amdgcn_mfma_f32_16x16x32_bf16(ah[tm], bl[tn], acc[tm][tn], 0, 0, 0);
                acc[tm][tn] = __builtin_amdgcn_mfma_f32_16x16x32_bf16(al[tm], bh[tn], acc[tm][tn], 0, 0, 0);
            }
    }
    // C/D layout: col = lane&15, row = (lane>>4)*4 + reg  [m89/m91-verified]
    int grow0 = mt * 128 + wy * 64 + q * 4;
    int gcol0 = nt * 128 + wx * 64 + fl;
#pragma unroll
    for (int tm = 0; tm < 4; ++tm)
#pragma unroll
        for (int tn = 0; tn < 4; ++tn) {
            size_t base = (size_t)(grow0 + tm * 16) * V_ + gcol0 + tn * 16;
#pragma unroll
            for (int r = 0; r < 4; ++r)
                out[base + (size_t)r * V_] = acc[tm][tn][r];
        }
}

extern "C" void kernel_launch(void* const* d_in, const int* in_sizes, int n_in,
                              void* d_out, int out_size, void* d_ws, size_t ws_size,
                              hipStream_t stream) {
    const int* ids = (const int*)d_in[0];
    const float* embed = (const float*)d_in[1];
    const float* wq = (const float*)d_in[2];     // (L,H,D)
    const float* bq = (const float*)d_in[3];
    const float* alpha = (const float*)d_in[4];  // (L,H)
    const float* wout = (const float*)d_in[5];   // (L,D)
    const float* bout = (const float*)d_in[6];
    const float* ffnW = (const float*)d_in[7];   // (L,N,D)
    const float* ffnB = (const float*)d_in[8];
    const float* acos_ = (const float*)d_in[9];
    const float* asin_ = (const float*)d_in[10];
    const float* pcos = (const float*)d_in[11];  // (L,D,N)
    const float* psin = (const float*)d_in[12];
    const float* escl = (const float*)d_in[13];  // (L,)
    const float* rscl = (const float*)d_in[14];
    const float* oprj = (const float*)d_in[15];  // (V,D)
    float* out = (float*)d_out;
    float* ws = (float*)d_ws;

    // workspace layout (floats)
    float* EG = ws;                       // B*S*256      = 524288
    float* SR = EG + 524288;              // B*S*D        = 262144
    float* SI = SR + 262144;
    float* X  = SI + 262144;
    float* KB = X + 262144;               // B*S*256      = 524288
    float* Q  = KB + 524288;              // B*H*S*256    = 1048576
    float* SC = Q + 1048576;              // B*H*S*S      = 4194304
    float* RT = SC + 4194304;             // B*H*S*256    = 1048576
    float* CB = RT + 1048576;             // B*S*D        = 262144
    float* CS = CB + 262144;              // B*S*N        = 524288
    float* SS = CS + 524288;
    float* RS = SS + 524288;              // B*S*D        = 262144
    float* T_IW = RS + 262144;            // 6 x L*D*N (=65536 each)
    float* T_BP = T_IW + 65536;
    float* T_AC = T_BP + 65536;
    float* T_AS = T_AC + 65536;
    float* T_PC = T_AS + 65536;
    float* T_PS = T_PC + 65536;
    // bf16-split buffers for k_out, overlaid on Q..SC (dead by the time k_cvt runs)
    __bf16* XH = (__bf16*)Q;              // 262144 bf16
    __bf16* XL = XH + 262144;
    __bf16* PH = XL + 262144;             // 4096000 bf16
    __bf16* PL = PH + 4096000;

    k_prep<<<256, 256, 0, stream>>>(ffnW, ffnB, acos_, asin_, pcos, psin,
                                    T_IW, T_BP, T_AC, T_AS, T_PC, T_PS);
    k_gather<<<2048, 256, 0, stream>>>(ids, embed, EG);
    k_euler<<<2, 128, 0, stream>>>(EG, SR, SI, X, KB);

    for (int l = 0; l < L_; ++l) {
        k_q<<<4096, 256, 0, stream>>>(SR, SI, wq + l * H_ * D_, bq + l * H_ * D_, Q);
        k_scores<<<dim3(16, 16, 4), 256, 0, stream>>>(Q, KB, SC);
        k_softmax<<<4096, 256, 0, stream>>>(SC);
        k_pv<<<dim3(4, 16, 4), 256, 0, stream>>>(SC, KB, RT);
        k_ema<<<2048, 256, 0, stream>>>(RT, alpha + l * H_, CB);
        k_ffn1<<<256, 256, 0, stream>>>(X, T_IW + l * 32768, T_BP + l * 32768,
                                        T_AC + l * 32768, T_AS + l * 32768, CS, SS);
        k_ffn2<<<256, 128, 0, stream>>>(CS, SS, T_PC + l * 32768, T_PS + l * 32768, RS);
        k_update<<<1024, 256, 0, stream>>>(X, CB, RS, wout + l * D_, bout + l * D_,
                                           escl + l, rscl + l);
    }
    k_cvt<<<17024, 256, 0, stream>>>(X, oprj, XH, XL, PH, PL);
    k_out_mfma<<<dim3(16, 250), 256, 0, stream>>>(XH, XL, PH, PL, out);
}